// Round 7
// baseline (1943.048 us; speedup 1.0000x reference)
//
#include <hip/hip_runtime.h>
#include <hip/hip_bf16.h>
#include <math.h>

#define NT 34000
#define NTYPES 3
#define NMP 2
#define NE 300000
#define HH 8
#define DD 64
#define HD 512
#define AV 128
#define NCLS 8
#define NTGT 1000
#define NN (NTYPES*NT)
#define NBLK 133   // ceil(NT/256)

typedef short short8 __attribute__((ext_vector_type(8)));
typedef float f32x4 __attribute__((ext_vector_type(4)));

__device__ __forceinline__ short f2bf(float f){
  unsigned u = __float_as_uint(f);
  unsigned r = u + 0x7FFFu + ((u>>16)&1u);
  return (short)(r>>16);
}
__device__ __forceinline__ float bf2f(short s){
  return __uint_as_float(((unsigned)(unsigned short)s)<<16);
}
__device__ __forceinline__ float fast_tanh(float x){
  x = fminf(15.f, fmaxf(-15.f, x));
  float t = __expf(2.f*x);
  return (t-1.f)/(t+1.f);
}

// ---------------- CSR build ----------------
__global__ void k_zero(int* __restrict__ p, int n){
  int i = blockIdx.x*256+threadIdx.x; if(i<n) p[i]=0;
}

__global__ void k_hist(const int* __restrict__ mp, int* __restrict__ counts){
  int e = blockIdx.x*256+threadIdx.x; int g = blockIdx.y;
  if(e>=NE) return;
  int i = g>>1;
  int dst = mp[((size_t)g*NE+e)*3] - i*NT;
  atomicAdd(&counts[g*NT+dst],1);
}

// block-level reduce: bsum[g][blk] = sum of counts[g][blk*256 .. +255]
__global__ __launch_bounds__(256) void k_blkred(const int* __restrict__ counts, int* __restrict__ bsum){
  int g=blockIdx.y, blk=blockIdx.x, t=threadIdx.x;
  int idx=blk*256+t;
  int v=(idx<NT)? counts[g*NT+idx]:0;
  #pragma unroll
  for(int off=32;off;off>>=1) v+=__shfl_down(v,off,64);
  __shared__ int sh[4];
  if((t&63)==0) sh[t>>6]=v;
  __syncthreads();
  if(t==0) bsum[g*NBLK+blk]=sh[0]+sh[1]+sh[2]+sh[3];
}

// exclusive scan of the 133 block sums per group (in place)
__global__ __launch_bounds__(256) void k_scansums(int* __restrict__ bsum){
  int g=blockIdx.x; int t=threadIdx.x;
  __shared__ int s[256];
  int v=(t<NBLK)? bsum[g*NBLK+t]:0;
  s[t]=v; __syncthreads();
  for(int off=1;off<256;off<<=1){
    int tmp=(t>=off)?s[t-off]:0; __syncthreads();
    s[t]+=tmp; __syncthreads();
  }
  if(t<NBLK) bsum[g*NBLK+t]=s[t]-v;
}

// rescan each chunk, add block prefix, write offs, zero counts for scatter reuse
__global__ __launch_bounds__(256) void k_scanapply(int* __restrict__ counts, const int* __restrict__ bsum,
                                                   int* __restrict__ offs){
  int g=blockIdx.y, blk=blockIdx.x, t=threadIdx.x;
  int idx=blk*256+t;
  int v=(idx<NT)? counts[g*NT+idx]:0;
  __shared__ int s[256];
  s[t]=v; __syncthreads();
  for(int off=1;off<256;off<<=1){
    int tmp=(t>=off)?s[t-off]:0; __syncthreads();
    s[t]+=tmp; __syncthreads();
  }
  int excl = s[t]-v + bsum[g*NBLK+blk];
  if(idx<NT){ offs[g*(NT+1)+idx]=excl; counts[g*NT+idx]=0; }
  if(idx==NT-1) offs[g*(NT+1)+NT]=excl+v;
}

// scatter only the mid-node pair per edge (dst is implicit in the segment)
__global__ void k_scatter(const int* __restrict__ mp, const int* __restrict__ offs,
                          int* __restrict__ counts, int2* __restrict__ mids){
  int e = blockIdx.x*256+threadIdx.x; int g=blockIdx.y;
  if(e>=NE) return;
  int i=g>>1;
  const int* row = mp + ((size_t)g*NE+e)*3;
  int dst = row[0]-i*NT;
  int pos = offs[g*(NT+1)+dst] + atomicAdd(&counts[g*NT+dst],1);
  mids[(size_t)g*NE+pos]=make_int2(row[1],row[2]);
}

// -------- pack all 4 fc weight mats into MFMA B-fragment hi/lo bf16 layout ---------
__global__ void k_packWall(const float* __restrict__ W0, const float* __restrict__ W1,
                           const float* __restrict__ W2, const float* __restrict__ WL,
                           short* __restrict__ p0, short* __restrict__ p1,
                           short* __restrict__ p2, short* __restrict__ pL){
  const float* W; short* wpk; int K;
  int which = blockIdx.y;
  if(which==0){W=W0;wpk=p0;K=512;}
  else if(which==1){W=W1;wpk=p1;K=256;}
  else if(which==2){W=W2;wpk=p2;K=128;}
  else {W=WL;wpk=pL;K=512;}
  int nk = K>>5;
  int total = nk*256;
  int tid = blockIdx.x*256+threadIdx.x;
  if(tid>=total) return;
  int lane = tid&63; int c=(tid>>6)&3; int kt=tid>>8;
  int col = c*16 + (lane&15);
  int kbase = kt*32 + ((lane>>4)<<3);
  short8 hi, lo;
  #pragma unroll
  for(int j=0;j<8;j++){
    float w = W[(size_t)(kbase+j)*64+col];
    short h = f2bf(w); hi[j]=h;
    lo[j] = f2bf(w - bf2f(h));
  }
  ((short8*)wpk)[tid] = hi;
  ((short8*)wpk)[total+tid] = lo;
}

// -------- MFMA fc (split-bf16 ~ f32 precision): Y[rows,64]=X[rows,K]@W+b, opt ELU --
__global__ __launch_bounds__(256) void k_mm64f(const float* __restrict__ X, const short* __restrict__ wpk,
               const float* __restrict__ b, float* __restrict__ Y, int rows, int K, int act){
  int wave = threadIdx.x>>6, lane = threadIdx.x&63;
  int row0 = blockIdx.x*64 + wave*16;
  if(row0>=rows) return;
  int r = row0 + (lane&15);
  int rc = min(r, rows-1);
  const float* xr = X + (size_t)rc*K + ((lane>>4)<<3);
  int nk = K>>5;
  const short8* wh = (const short8*)wpk;
  const short8* wl = wh + (size_t)nk*256;
  f32x4 acc[4];
  #pragma unroll
  for(int c=0;c<4;c++) acc[c]=(f32x4){0.f,0.f,0.f,0.f};
  for(int kt=0;kt<nk;kt++){
    float4 f0=*(const float4*)(xr + kt*32);
    float4 f1=*(const float4*)(xr + kt*32 + 4);
    float xs[8]={f0.x,f0.y,f0.z,f0.w,f1.x,f1.y,f1.z,f1.w};
    short8 ah, al;
    #pragma unroll
    for(int j=0;j<8;j++){
      short h=f2bf(xs[j]); ah[j]=h;
      al[j]=f2bf(xs[j]-bf2f(h));
    }
    const short8* whk = wh + (size_t)kt*256 + lane;
    const short8* wlk = wl + (size_t)kt*256 + lane;
    #pragma unroll
    for(int c=0;c<4;c++){
      short8 bh = whk[c*64];
      short8 bl = wlk[c*64];
      acc[c]=__builtin_amdgcn_mfma_f32_16x16x32_bf16(ah,bh,acc[c],0,0,0);
      acc[c]=__builtin_amdgcn_mfma_f32_16x16x32_bf16(al,bh,acc[c],0,0,0);
      acc[c]=__builtin_amdgcn_mfma_f32_16x16x32_bf16(ah,bl,acc[c],0,0,0);
    }
  }
  int rbase = row0 + ((lane>>4)<<2);
  int colb = lane&15;
  #pragma unroll
  for(int c=0;c<4;c++){
    int col = c*16+colb;
    float bb = b[col];
    #pragma unroll
    for(int q=0;q<4;q++){
      int rw = rbase+q;
      if(rw<rows){
        float v = acc[c][q]+bb;
        if(act) v = v>0.f? v : (__expf(v)-1.f);
        Y[(size_t)rw*64+col]=v;
      }
    }
  }
}

// -------- same, but X = beta0*X0 + beta1*X1 (beta read from device), K=512 ---------
__global__ __launch_bounds__(256) void k_mm64fB(const float* __restrict__ Xa, const float* __restrict__ Xb,
               const float* __restrict__ beta, int slot, const short* __restrict__ wpk,
               const float* __restrict__ b, float* __restrict__ Y, int rows, int act){
  const int K=512, nk=16;
  float b0=beta[slot*2], b1=beta[slot*2+1];
  int wave = threadIdx.x>>6, lane = threadIdx.x&63;
  int row0 = blockIdx.x*64 + wave*16;
  if(row0>=rows) return;
  int r = row0 + (lane&15);
  int rc = min(r, rows-1);
  const float* xra = Xa + (size_t)rc*K + ((lane>>4)<<3);
  const float* xrb = Xb + (size_t)rc*K + ((lane>>4)<<3);
  const short8* wh = (const short8*)wpk;
  const short8* wl = wh + (size_t)nk*256;
  f32x4 acc[4];
  #pragma unroll
  for(int c=0;c<4;c++) acc[c]=(f32x4){0.f,0.f,0.f,0.f};
  for(int kt=0;kt<nk;kt++){
    float4 a0=*(const float4*)(xra + kt*32);
    float4 a1=*(const float4*)(xra + kt*32 + 4);
    float4 c0=*(const float4*)(xrb + kt*32);
    float4 c1=*(const float4*)(xrb + kt*32 + 4);
    float xs[8]={b0*a0.x+b1*c0.x, b0*a0.y+b1*c0.y, b0*a0.z+b1*c0.z, b0*a0.w+b1*c0.w,
                 b0*a1.x+b1*c1.x, b0*a1.y+b1*c1.y, b0*a1.z+b1*c1.z, b0*a1.w+b1*c1.w};
    short8 ah, al;
    #pragma unroll
    for(int j=0;j<8;j++){
      short h=f2bf(xs[j]); ah[j]=h;
      al[j]=f2bf(xs[j]-bf2f(h));
    }
    const short8* whk = wh + (size_t)kt*256 + lane;
    const short8* wlk = wl + (size_t)kt*256 + lane;
    #pragma unroll
    for(int c=0;c<4;c++){
      short8 bh = whk[c*64];
      short8 bl = wlk[c*64];
      acc[c]=__builtin_amdgcn_mfma_f32_16x16x32_bf16(ah,bh,acc[c],0,0,0);
      acc[c]=__builtin_amdgcn_mfma_f32_16x16x32_bf16(al,bh,acc[c],0,0,0);
      acc[c]=__builtin_amdgcn_mfma_f32_16x16x32_bf16(ah,bl,acc[c],0,0,0);
    }
  }
  int rbase = row0 + ((lane>>4)<<2);
  int colb = lane&15;
  #pragma unroll
  for(int c=0;c<4;c++){
    int col = c*16+colb;
    float bb = b[col];
    #pragma unroll
    for(int q=0;q<4;q++){
      int rw = rbase+q;
      if(rw<rows){
        float v = acc[c][q]+bb;
        if(act) v = v>0.f? v : (__expf(v)-1.f);
        Y[(size_t)rw*64+col]=v;
      }
    }
  }
}

// -------- per-node attention projections: ptab[g][node][0..7]=h·a1, [8..15]=h·a2 ----
__global__ __launch_bounds__(256) void k_pre(const float* __restrict__ h, const float* __restrict__ a1,
              const float* __restrict__ a2, float* __restrict__ ptab, int ngroups){
  int node = blockIdx.x*256+threadIdx.x;
  if(node>=NN) return;
  const float* hr = h + (size_t)node*64;
  float4 hv[16];
  #pragma unroll
  for(int q=0;q<16;q++) hv[q]=((const float4*)hr)[q];
  for(int g=0; g<ngroups; g++){
    const float* A1 = a1 + (size_t)g*512;
    const float* A2 = a2 + (size_t)g*512;
    float out[16];
    #pragma unroll
    for(int o=0;o<8;o++){
      float acc=0.f;
      #pragma unroll
      for(int q=0;q<16;q++){
        float4 w=((const float4*)A1)[o*16+q];
        acc += hv[q].x*w.x+hv[q].y*w.y+hv[q].z*w.z+hv[q].w*w.w;
      }
      out[o]=acc;
    }
    #pragma unroll
    for(int o=0;o<8;o++){
      float acc=0.f;
      #pragma unroll
      for(int q=0;q<16;q++){
        float4 w=((const float4*)A2)[o*16+q];
        acc += hv[q].x*w.x+hv[q].y*w.y+hv[q].z*w.z+hv[q].w*w.w;
      }
      out[8+o]=acc;
    }
    float* dp = ptab + ((size_t)g*NN+node)*16;
    #pragma unroll
    for(int q=0;q<4;q++)
      ((float4*)dp)[q]=make_float4(out[q*4],out[q*4+1],out[q*4+2],out[q*4+3]);
  }
}

// -------- fused edge-logit + online segment softmax + accumulate + elu -------------
// e_h = leakyrelu( pA(n)[h] + (pB(n)[h] + pB(m1)[h] + pB(m2)[h])/3 )
// st[p][n][h*64+lane] = elu( (sum_e alpha_e*(h[m1]+h[m2])[lane] + h[n][lane]) / 3 )
__global__ __launch_bounds__(256) void k_seg(const int* __restrict__ offs_all, const float* __restrict__ ptab,
   const int2* __restrict__ mids_all, const float* __restrict__ h, float* __restrict__ st, int type){
  int wave = threadIdx.x>>6, lane = threadIdx.x&63;
  int n = blockIdx.x*4 + wave;
  if(n>=NT) return;
  int p = blockIdx.y; int g = type*2+p;
  const int* offs = offs_all + (size_t)g*(NT+1);
  const int2* mids_g = mids_all + (size_t)g*NE;
  const float* pt = ptab + (size_t)g*NN*16;
  float* stp = st + (size_t)p*NT*512;

  int off = offs[n], end = offs[n+1];
  const float third = 1.f/3.f;

  // per-node projections (wave-uniform broadcast loads)
  const float* pn = pt + (size_t)(type*NT+n)*16;
  float4 pA0=((const float4*)pn)[0], pA1=((const float4*)pn)[1];
  float4 pB0=((const float4*)pn)[2], pB1=((const float4*)pn)[3];
  float base[8];
  base[0]=pA0.x+pB0.x*third; base[1]=pA0.y+pB0.y*third;
  base[2]=pA0.z+pB0.z*third; base[3]=pA0.w+pB0.w*third;
  base[4]=pA1.x+pB1.x*third; base[5]=pA1.y+pB1.y*third;
  base[6]=pA1.z+pB1.z*third; base[7]=pA1.w+pB1.w*third;

  float m[8], den[8], o[8];
  #pragma unroll
  for(int hh=0;hh<8;hh++){ m[hh]=-1e30f; den[hh]=0.f; o[hh]=0.f; }

  for(int s=off;s<end;s++){
    int2 mm = mids_g[s];
    const float* q1 = pt + (size_t)mm.x*16 + 8;
    const float* q2 = pt + (size_t)mm.y*16 + 8;
    float4 qa=((const float4*)q1)[0], qb=((const float4*)q1)[1];
    float4 qc=((const float4*)q2)[0], qd=((const float4*)q2)[1];
    float hvm = h[(size_t)mm.x*64+lane] + h[(size_t)mm.y*64+lane];
    float e[8];
    e[0]=base[0]+(qa.x+qc.x)*third; e[1]=base[1]+(qa.y+qc.y)*third;
    e[2]=base[2]+(qa.z+qc.z)*third; e[3]=base[3]+(qa.w+qc.w)*third;
    e[4]=base[4]+(qb.x+qd.x)*third; e[5]=base[5]+(qb.y+qd.y)*third;
    e[6]=base[6]+(qb.z+qd.z)*third; e[7]=base[7]+(qb.w+qd.w)*third;
    #pragma unroll
    for(int hh=0;hh<8;hh++){
      float ev = e[hh]>0.f? e[hh] : 0.2f*e[hh];
      float mn = fmaxf(m[hh], ev);
      float sc = __expf(m[hh]-mn);      // first edge: exp(-huge)=0
      float w  = __expf(ev-mn);
      den[hh] = den[hh]*sc + w;
      o[hh]   = o[hh]*sc + w*hvm;
      m[hh]   = mn;
    }
  }

  float hn = h[((size_t)type*NT+(size_t)n)*64+lane];
  #pragma unroll
  for(int hh=0;hh<8;hh++){
    float v = (end>off)? (o[hh]/fmaxf(den[hh],1e-9f) + hn)*third : 0.f;
    v = v>0.f? v : (__expf(v)-1.f);
    stp[(size_t)n*512 + hh*64 + lane] = v;
  }
}

// -------- pack mpW (512x128 f32) into MFMA B-fragment layout (bf16); zero accv -----
__global__ __launch_bounds__(256) void k_pack(const float* __restrict__ W, short* __restrict__ bpk,
                                              float* __restrict__ accv){
  int tid = blockIdx.x*256+threadIdx.x;   // 0..8191
  int lane = tid&63; int c=(tid>>6)&7; int t=tid>>9;
  int kbase = t*32 + ((lane>>4)<<3);
  int col = c*16 + (lane&15);
  short8 v;
  #pragma unroll
  for(int jj=0;jj<8;jj++) v[jj]=f2bf(W[(size_t)(kbase+jj)*128+col]);
  ((short8*)bpk)[tid]=v;
  if(tid<256) accv[tid]=0.f;
}

// -------- bf16 MFMA + LDS-staged B: accv[p][col] += sum_n tanh(st@W + b) -----------
__global__ __launch_bounds__(256) void k_tanhmm(const float* __restrict__ st, const short* __restrict__ bpk,
                        const float* __restrict__ bias, float* __restrict__ accv){
  __shared__ short8 Bsh[2048];          // 4 kt-chunks x 8 c x 64 lanes x 16B = 32 KB
  int wave=threadIdx.x>>6, lane=threadIdx.x&63;
  int p=blockIdx.y;
  const float* stp = st + (size_t)p*NT*512;
  int row0 = (blockIdx.x*4+wave)*16;
  int active = (row0<NT);
  int rA = row0 + (lane&15); if(rA>NT-1) rA=NT-1;
  const float* arow = stp + (size_t)rA*512 + ((lane>>4)<<3);
  f32x4 acc[8];
  #pragma unroll
  for(int c=0;c<8;c++) acc[c]=(f32x4){0.f,0.f,0.f,0.f};
  const short8* bp = (const short8*)bpk;
  for(int kc=0;kc<16;kc+=4){
    __syncthreads();
    #pragma unroll
    for(int q=0;q<8;q++){
      int idx = q*256 + threadIdx.x;
      Bsh[idx] = bp[(size_t)kc*512 + idx];
    }
    __syncthreads();
    if(active){
      #pragma unroll
      for(int ktl=0;ktl<4;ktl++){
        int kt=kc+ktl;
        float4 f0 = *(const float4*)(arow + kt*32);
        float4 f1 = *(const float4*)(arow + kt*32 + 4);
        short8 a;
        a[0]=f2bf(f0.x); a[1]=f2bf(f0.y); a[2]=f2bf(f0.z); a[3]=f2bf(f0.w);
        a[4]=f2bf(f1.x); a[5]=f2bf(f1.y); a[6]=f2bf(f1.z); a[7]=f2bf(f1.w);
        #pragma unroll
        for(int c=0;c<8;c++){
          short8 bfr = Bsh[ktl*512 + c*64 + lane];
          acc[c]=__builtin_amdgcn_mfma_f32_16x16x32_bf16(a,bfr,acc[c],0,0,0);
        }
      }
    }
  }
  if(active){
    int rbase = row0 + ((lane>>4)<<2);
    int colb = lane&15;
    #pragma unroll
    for(int c=0;c<8;c++){
      int col=c*16+colb;
      float bb=bias[col];
      float s=0.f;
      #pragma unroll
      for(int r=0;r<4;r++){
        if(rbase+r<NT) s += fast_tanh(acc[c][r]+bb);
      }
      s += __shfl_xor(s,16,64);
      s += __shfl_xor(s,32,64);
      if(lane<16) atomicAdd(&accv[p*128+col], s);
    }
  }
}

// -------- beta = softmax over P of (mean tanh)·q ------------------------------------
__global__ void k_beta(const float* __restrict__ accv, const float* __restrict__ q,
                       float* __restrict__ beta, int slot){
  __shared__ float r0[128], r1[128];
  int t=threadIdx.x;
  r0[t]=accv[t]*q[t]; r1[t]=accv[128+t]*q[t];
  __syncthreads();
  for(int off=64;off>0;off>>=1){
    if(t<off){ r0[t]+=r0[t+off]; r1[t]+=r1[t+off]; }
    __syncthreads();
  }
  if(t==0){
    float s0=r0[0]/(float)NT, s1=r1[0]/(float)NT;
    float mm=fmaxf(s0,s1);
    float e0=__expf(s0-mm), e1=__expf(s1-mm);
    float d=e0+e1;
    beta[slot*2]=e0/d; beta[slot*2+1]=e1/d;
  }
}

// -------- final: logits[t] = (b0*st0[row]+b1*st1[row]) @ lW1 + lb1 -----------------
__global__ __launch_bounds__(64) void k_final(const float* __restrict__ st0, const float* __restrict__ st1,
      const float* __restrict__ beta, const float* __restrict__ lW1, const float* __restrict__ lb1,
      const int* __restrict__ tgt, float* __restrict__ out){
  int t=blockIdx.x; int lane=threadIdx.x;
  int row=tgt[t];
  float b0=beta[6], b1=beta[7];
  float acc[8]={0.f,0.f,0.f,0.f,0.f,0.f,0.f,0.f};
  #pragma unroll
  for(int kk=0;kk<8;kk++){
    int k=kk*64+lane;
    float hm=b0*st0[(size_t)row*512+k]+b1*st1[(size_t)row*512+k];
    const float4* wp=(const float4*)(lW1+(size_t)k*8);
    float4 w0=wp[0], w1=wp[1];
    acc[0]+=hm*w0.x; acc[1]+=hm*w0.y; acc[2]+=hm*w0.z; acc[3]+=hm*w0.w;
    acc[4]+=hm*w1.x; acc[5]+=hm*w1.y; acc[6]+=hm*w1.z; acc[7]+=hm*w1.w;
  }
  #pragma unroll
  for(int c=0;c<8;c++){
    #pragma unroll
    for(int off=32;off>0;off>>=1) acc[c]+=__shfl_xor(acc[c],off,64);
  }
  if(lane<8){
    float v=0.f;
    #pragma unroll
    for(int c=0;c<8;c++) if(lane==c) v=acc[c];
    out[t*8+lane]=v+lb1[lane];
  }
}

extern "C" void kernel_launch(void* const* d_in, const int* in_sizes, int n_in,
                              void* d_out, int out_size, void* d_ws, size_t ws_size,
                              hipStream_t stream) {
  const float* X0=(const float*)d_in[0];
  const float* X1=(const float*)d_in[1];
  const float* X2=(const float*)d_in[2];
  const float* fcW0=(const float*)d_in[3]; const float* fcb0=(const float*)d_in[4];
  const float* fcW1=(const float*)d_in[5]; const float* fcb1=(const float*)d_in[6];
  const float* fcW2=(const float*)d_in[7]; const float* fcb2=(const float*)d_in[8];
  const float* attn1=(const float*)d_in[9];
  const float* attn2=(const float*)d_in[10];
  const float* mpW=(const float*)d_in[11];
  const float* mpb=(const float*)d_in[12];
  const float* mpq=(const float*)d_in[13];
  const float* lW0=(const float*)d_in[14]; const float* lb0=(const float*)d_in[15];
  const float* lW1=(const float*)d_in[16]; const float* lb1=(const float*)d_in[17];
  const int* mp=(const int*)d_in[18];
  const int* tgt=(const int*)d_in[19];
  float* out=(float*)d_out;

  // workspace layout (total ~273.3 MB). Liveness-checked carve-outs:
  char* ws=(char*)d_ws;
  float* h0   =(float*)(ws+0);              // N*64 f32      (live from k_mm64f on)
  float* h1   =(float*)(ws+26112000);       // N*64 f32
  float* ptab =(float*)(ws+52224000);       // 6*N*16 f32
  int*   offs =(int*  )(ws+91392000);       // 6*(NT+1)
  int*   counts=(int* )(ws+92208128);       // 6*NT (live during CSR build ONLY)
  int2*  mids =(int2* )(ws+100224128);      // 6*E int2   (dsts/eall regions now unused)
  float* st   =(float*)(ws+133824128);      // 2*NT*512 f32  (live from k_seg on)
  short* bpk  =(short*)(ws+273088128);      // mpW fragments
  float* accv =(float*)(ws+273219200);      // 2*128 f32
  float* beta =(float*)(ws+273220224);      // 8 f32
  // packed fc weights: counts region, first written AFTER k_scatter (counts dead). OK.
  short* wpk0 =(short*)(ws+92208128);       // [.., +128KB)  K=512
  short* wpk1 =(short*)(ws+92339200);       // [.., +64KB)   K=256
  short* wpkL =(short*)(ws+92404736);       // [.., +128KB)  K=512
  short* wpk2 =(short*)(ws+92535808);       // [.., +32KB)   K=128
  // bsum: used ONLY during CSR build; placed in st region (first written by k_seg later)
  int*   bsum =(int*  )(ws+133824128);      // 6*NBLK ints = 3192 B

  dim3 b256(256);
  // CSR build (mp_idx is layer-invariant; built once per launch)
  k_zero<<<dim3((6*NT+255)/256),b256,0,stream>>>(counts,6*NT);
  k_hist<<<dim3((NE+255)/256,6),b256,0,stream>>>(mp,counts);
  k_blkred<<<dim3(NBLK,6),b256,0,stream>>>(counts,bsum);
  k_scansums<<<dim3(6),b256,0,stream>>>(bsum);
  k_scanapply<<<dim3(NBLK,6),b256,0,stream>>>(counts,bsum,offs);
  k_scatter<<<dim3((NE+255)/256,6),b256,0,stream>>>(mp,offs,counts,mids);

  // pack fc weights (counts region dead from here on)
  k_packWall<<<dim3(16,4),b256,0,stream>>>(fcW0,fcW1,fcW2,lW0,wpk0,wpk1,wpk2,wpkL);

  // per-type feature transforms -> h0 (MFMA split-bf16)
  k_mm64f<<<dim3(532),b256,0,stream>>>(X0,wpk0,fcb0,h0,NT,512,0);
  k_mm64f<<<dim3(532),b256,0,stream>>>(X1,wpk1,fcb1,h0+(size_t)NT*64,NT,256,0);
  k_mm64f<<<dim3(532),b256,0,stream>>>(X2,wpk2,fcb2,h0+(size_t)2*NT*64,NT,128,0);

  // ---- layer 0 ----
  k_pre<<<dim3((NN+255)/256),b256,0,stream>>>(h0,attn1,attn2,ptab,6);
  for(int type=0;type<3;type++){
    k_seg<<<dim3(NT/4,2),b256,0,stream>>>(offs,ptab,mids,h0,st,type);
    k_pack<<<dim3(32),b256,0,stream>>>(mpW+(size_t)(0*3+type)*512*128,bpk,accv);
    k_tanhmm<<<dim3(532,2),b256,0,stream>>>(st,bpk,mpb+(0*3+type)*128,accv);
    k_beta<<<dim3(1),dim3(128),0,stream>>>(accv,mpq+(0*3+type)*128,beta,type);
    k_mm64fB<<<dim3(532),b256,0,stream>>>(st,st+(size_t)NT*512,beta,type,wpkL,lb0,
                                          h1+(size_t)type*NT*64,NT,1);
  }

  // ---- layer 1 (only type 0 reaches the output) ----
  k_pre<<<dim3((NN+255)/256),b256,0,stream>>>(h1,attn1+(size_t)6*512,attn2+(size_t)6*512,ptab,2);
  k_seg<<<dim3(NT/4,2),b256,0,stream>>>(offs,ptab,mids,h1,st,0);
  k_pack<<<dim3(32),b256,0,stream>>>(mpW+(size_t)(1*3+0)*512*128,bpk,accv);
  k_tanhmm<<<dim3(532,2),b256,0,stream>>>(st,bpk,mpb+(1*3+0)*128,accv);
  k_beta<<<dim3(1),dim3(128),0,stream>>>(accv,mpq+(1*3+0)*128,beta,3);
  k_final<<<dim3(NTGT),dim3(64),0,stream>>>(st,st+(size_t)NT*512,beta,lW1,lb1,tgt,out);
}

// Round 8
// 1524.737 us; speedup vs baseline: 1.2743x; 1.2743x over previous
//
#include <hip/hip_runtime.h>
#include <hip/hip_bf16.h>
#include <math.h>

#define NT 34000
#define NTYPES 3
#define NMP 2
#define NE 300000
#define HH 8
#define DD 64
#define HD 512
#define AV 128
#define NCLS 8
#define NTGT 1000
#define NN (NTYPES*NT)
#define NBLK 133   // ceil(NT/256)

typedef short short8 __attribute__((ext_vector_type(8)));
typedef float f32x4 __attribute__((ext_vector_type(4)));

__device__ __forceinline__ short f2bf(float f){
  unsigned u = __float_as_uint(f);
  unsigned r = u + 0x7FFFu + ((u>>16)&1u);
  return (short)(r>>16);
}
__device__ __forceinline__ float bf2f(short s){
  return __uint_as_float(((unsigned)(unsigned short)s)<<16);
}
__device__ __forceinline__ float fast_tanh(float x){
  x = fminf(15.f, fmaxf(-15.f, x));
  float t = __expf(2.f*x);
  return (t-1.f)/(t+1.f);
}

// ---------------- CSR build ----------------
__global__ void k_zero(int* __restrict__ p, int n){
  int i = blockIdx.x*256+threadIdx.x; if(i<n) p[i]=0;
}

__global__ void k_hist(const int* __restrict__ mp, int* __restrict__ counts){
  int e = blockIdx.x*256+threadIdx.x; int g = blockIdx.y;
  if(e>=NE) return;
  int i = g>>1;
  int dst = mp[((size_t)g*NE+e)*3] - i*NT;
  atomicAdd(&counts[g*NT+dst],1);
}

// block-level reduce: bsum[g][blk] = sum of counts[g][blk*256 .. +255]
__global__ __launch_bounds__(256) void k_blkred(const int* __restrict__ counts, int* __restrict__ bsum){
  int g=blockIdx.y, blk=blockIdx.x, t=threadIdx.x;
  int idx=blk*256+t;
  int v=(idx<NT)? counts[g*NT+idx]:0;
  #pragma unroll
  for(int off=32;off;off>>=1) v+=__shfl_down(v,off,64);
  __shared__ int sh[4];
  if((t&63)==0) sh[t>>6]=v;
  __syncthreads();
  if(t==0) bsum[g*NBLK+blk]=sh[0]+sh[1]+sh[2]+sh[3];
}

// exclusive scan of the 133 block sums per group (in place)
__global__ __launch_bounds__(256) void k_scansums(int* __restrict__ bsum){
  int g=blockIdx.x; int t=threadIdx.x;
  __shared__ int s[256];
  int v=(t<NBLK)? bsum[g*NBLK+t]:0;
  s[t]=v; __syncthreads();
  for(int off=1;off<256;off<<=1){
    int tmp=(t>=off)?s[t-off]:0; __syncthreads();
    s[t]+=tmp; __syncthreads();
  }
  if(t<NBLK) bsum[g*NBLK+t]=s[t]-v;
}

// rescan each chunk, add block prefix, write offs, zero counts for scatter reuse
__global__ __launch_bounds__(256) void k_scanapply(int* __restrict__ counts, const int* __restrict__ bsum,
                                                   int* __restrict__ offs){
  int g=blockIdx.y, blk=blockIdx.x, t=threadIdx.x;
  int idx=blk*256+t;
  int v=(idx<NT)? counts[g*NT+idx]:0;
  __shared__ int s[256];
  s[t]=v; __syncthreads();
  for(int off=1;off<256;off<<=1){
    int tmp=(t>=off)?s[t-off]:0; __syncthreads();
    s[t]+=tmp; __syncthreads();
  }
  int excl = s[t]-v + bsum[g*NBLK+blk];
  if(idx<NT){ offs[g*(NT+1)+idx]=excl; counts[g*NT+idx]=0; }
  if(idx==NT-1) offs[g*(NT+1)+NT]=excl+v;
}

// scatter only the mid-node pair per edge (dst is implicit in the segment)
__global__ void k_scatter(const int* __restrict__ mp, const int* __restrict__ offs,
                          int* __restrict__ counts, int2* __restrict__ mids){
  int e = blockIdx.x*256+threadIdx.x; int g=blockIdx.y;
  if(e>=NE) return;
  int i=g>>1;
  const int* row = mp + ((size_t)g*NE+e)*3;
  int dst = row[0]-i*NT;
  int pos = offs[g*(NT+1)+dst] + atomicAdd(&counts[g*NT+dst],1);
  mids[(size_t)g*NE+pos]=make_int2(row[1],row[2]);
}

// -------- pack all 4 fc weight mats into MFMA B-fragment hi/lo bf16 layout ---------
__global__ void k_packWall(const float* __restrict__ W0, const float* __restrict__ W1,
                           const float* __restrict__ W2, const float* __restrict__ WL,
                           short* __restrict__ p0, short* __restrict__ p1,
                           short* __restrict__ p2, short* __restrict__ pL){
  const float* W; short* wpk; int K;
  int which = blockIdx.y;
  if(which==0){W=W0;wpk=p0;K=512;}
  else if(which==1){W=W1;wpk=p1;K=256;}
  else if(which==2){W=W2;wpk=p2;K=128;}
  else {W=WL;wpk=pL;K=512;}
  int nk = K>>5;
  int total = nk*256;
  int tid = blockIdx.x*256+threadIdx.x;
  if(tid>=total) return;
  int lane = tid&63; int c=(tid>>6)&3; int kt=tid>>8;
  int col = c*16 + (lane&15);
  int kbase = kt*32 + ((lane>>4)<<3);
  short8 hi, lo;
  #pragma unroll
  for(int j=0;j<8;j++){
    float w = W[(size_t)(kbase+j)*64+col];
    short h = f2bf(w); hi[j]=h;
    lo[j] = f2bf(w - bf2f(h));
  }
  ((short8*)wpk)[tid] = hi;
  ((short8*)wpk)[total+tid] = lo;
}

// -------- MFMA fc (split-bf16 ~ f32 precision): Y[rows,64]=X[rows,K]@W+b, opt ELU --
__global__ __launch_bounds__(256) void k_mm64f(const float* __restrict__ X, const short* __restrict__ wpk,
               const float* __restrict__ b, float* __restrict__ Y, int rows, int K, int act){
  int wave = threadIdx.x>>6, lane = threadIdx.x&63;
  int row0 = blockIdx.x*64 + wave*16;
  if(row0>=rows) return;
  int r = row0 + (lane&15);
  int rc = min(r, rows-1);
  const float* xr = X + (size_t)rc*K + ((lane>>4)<<3);
  int nk = K>>5;
  const short8* wh = (const short8*)wpk;
  const short8* wl = wh + (size_t)nk*256;
  f32x4 acc[4];
  #pragma unroll
  for(int c=0;c<4;c++) acc[c]=(f32x4){0.f,0.f,0.f,0.f};
  for(int kt=0;kt<nk;kt++){
    float4 f0=*(const float4*)(xr + kt*32);
    float4 f1=*(const float4*)(xr + kt*32 + 4);
    float xs[8]={f0.x,f0.y,f0.z,f0.w,f1.x,f1.y,f1.z,f1.w};
    short8 ah, al;
    #pragma unroll
    for(int j=0;j<8;j++){
      short h=f2bf(xs[j]); ah[j]=h;
      al[j]=f2bf(xs[j]-bf2f(h));
    }
    const short8* whk = wh + (size_t)kt*256 + lane;
    const short8* wlk = wl + (size_t)kt*256 + lane;
    #pragma unroll
    for(int c=0;c<4;c++){
      short8 bh = whk[c*64];
      short8 bl = wlk[c*64];
      acc[c]=__builtin_amdgcn_mfma_f32_16x16x32_bf16(ah,bh,acc[c],0,0,0);
      acc[c]=__builtin_amdgcn_mfma_f32_16x16x32_bf16(al,bh,acc[c],0,0,0);
      acc[c]=__builtin_amdgcn_mfma_f32_16x16x32_bf16(ah,bl,acc[c],0,0,0);
    }
  }
  int rbase = row0 + ((lane>>4)<<2);
  int colb = lane&15;
  #pragma unroll
  for(int c=0;c<4;c++){
    int col = c*16+colb;
    float bb = b[col];
    #pragma unroll
    for(int q=0;q<4;q++){
      int rw = rbase+q;
      if(rw<rows){
        float v = acc[c][q]+bb;
        if(act) v = v>0.f? v : (__expf(v)-1.f);
        Y[(size_t)rw*64+col]=v;
      }
    }
  }
}

// -------- same, but X = beta0*X0 + beta1*X1 (beta read from device), K=512 ---------
__global__ __launch_bounds__(256) void k_mm64fB(const float* __restrict__ Xa, const float* __restrict__ Xb,
               const float* __restrict__ beta, int slot, const short* __restrict__ wpk,
               const float* __restrict__ b, float* __restrict__ Y, int rows, int act){
  const int K=512, nk=16;
  float b0=beta[slot*2], b1=beta[slot*2+1];
  int wave = threadIdx.x>>6, lane = threadIdx.x&63;
  int row0 = blockIdx.x*64 + wave*16;
  if(row0>=rows) return;
  int r = row0 + (lane&15);
  int rc = min(r, rows-1);
  const float* xra = Xa + (size_t)rc*K + ((lane>>4)<<3);
  const float* xrb = Xb + (size_t)rc*K + ((lane>>4)<<3);
  const short8* wh = (const short8*)wpk;
  const short8* wl = wh + (size_t)nk*256;
  f32x4 acc[4];
  #pragma unroll
  for(int c=0;c<4;c++) acc[c]=(f32x4){0.f,0.f,0.f,0.f};
  for(int kt=0;kt<nk;kt++){
    float4 a0=*(const float4*)(xra + kt*32);
    float4 a1=*(const float4*)(xra + kt*32 + 4);
    float4 c0=*(const float4*)(xrb + kt*32);
    float4 c1=*(const float4*)(xrb + kt*32 + 4);
    float xs[8]={b0*a0.x+b1*c0.x, b0*a0.y+b1*c0.y, b0*a0.z+b1*c0.z, b0*a0.w+b1*c0.w,
                 b0*a1.x+b1*c1.x, b0*a1.y+b1*c1.y, b0*a1.z+b1*c1.z, b0*a1.w+b1*c1.w};
    short8 ah, al;
    #pragma unroll
    for(int j=0;j<8;j++){
      short h=f2bf(xs[j]); ah[j]=h;
      al[j]=f2bf(xs[j]-bf2f(h));
    }
    const short8* whk = wh + (size_t)kt*256 + lane;
    const short8* wlk = wl + (size_t)kt*256 + lane;
    #pragma unroll
    for(int c=0;c<4;c++){
      short8 bh = whk[c*64];
      short8 bl = wlk[c*64];
      acc[c]=__builtin_amdgcn_mfma_f32_16x16x32_bf16(ah,bh,acc[c],0,0,0);
      acc[c]=__builtin_amdgcn_mfma_f32_16x16x32_bf16(al,bh,acc[c],0,0,0);
      acc[c]=__builtin_amdgcn_mfma_f32_16x16x32_bf16(ah,bl,acc[c],0,0,0);
    }
  }
  int rbase = row0 + ((lane>>4)<<2);
  int colb = lane&15;
  #pragma unroll
  for(int c=0;c<4;c++){
    int col = c*16+colb;
    float bb = b[col];
    #pragma unroll
    for(int q=0;q<4;q++){
      int rw = rbase+q;
      if(rw<rows){
        float v = acc[c][q]+bb;
        if(act) v = v>0.f? v : (__expf(v)-1.f);
        Y[(size_t)rw*64+col]=v;
      }
    }
  }
}

// -------- per-node attention projections: ptab[g][node][0..7]=h·a1, [8..15]=h·a2 ----
__global__ __launch_bounds__(256) void k_pre(const float* __restrict__ h, const float* __restrict__ a1,
              const float* __restrict__ a2, float* __restrict__ ptab, int ngroups){
  int node = blockIdx.x*256+threadIdx.x;
  if(node>=NN) return;
  const float* hr = h + (size_t)node*64;
  float4 hv[16];
  #pragma unroll
  for(int q=0;q<16;q++) hv[q]=((const float4*)hr)[q];
  for(int g=0; g<ngroups; g++){
    const float* A1 = a1 + (size_t)g*512;
    const float* A2 = a2 + (size_t)g*512;
    float out[16];
    #pragma unroll
    for(int o=0;o<8;o++){
      float acc=0.f;
      #pragma unroll
      for(int q=0;q<16;q++){
        float4 w=((const float4*)A1)[o*16+q];
        acc += hv[q].x*w.x+hv[q].y*w.y+hv[q].z*w.z+hv[q].w*w.w;
      }
      out[o]=acc;
    }
    #pragma unroll
    for(int o=0;o<8;o++){
      float acc=0.f;
      #pragma unroll
      for(int q=0;q<16;q++){
        float4 w=((const float4*)A2)[o*16+q];
        acc += hv[q].x*w.x+hv[q].y*w.y+hv[q].z*w.z+hv[q].w*w.w;
      }
      out[8+o]=acc;
    }
    float* dp = ptab + ((size_t)g*NN+node)*16;
    #pragma unroll
    for(int q=0;q<4;q++)
      ((float4*)dp)[q]=make_float4(out[q*4],out[q*4+1],out[q*4+2],out[q*4+3]);
  }
}

// -------- fused edge-logit + segment softmax + accumulate + elu --------------------
// Pass A: lane=(j,h) parallel online (m,den) over edge subsequence j, merge over j.
// Pass B: per 8-edge chunk: B1 lane-parallel w=exp(e-M)/D (one expf), B2 serial
//         accumulate with alpha via shuffle (no expf in serial loop).
__global__ __launch_bounds__(256) void k_seg(const int* __restrict__ offs_all, const float* __restrict__ ptab,
   const int2* __restrict__ mids_all, const float* __restrict__ h, float* __restrict__ st, int type){
  int wave = threadIdx.x>>6, lane = threadIdx.x&63;
  int n = blockIdx.x*4 + wave;
  if(n>=NT) return;
  int p = blockIdx.y; int g = type*2+p;
  const int* offs = offs_all + (size_t)g*(NT+1);
  const int2* mids_g = mids_all + (size_t)g*NE;
  const float* pt = ptab + (size_t)g*NN*16;
  float* stp = st + (size_t)p*NT*512;

  int off = offs[n], end = offs[n+1];
  const float third = 1.f/3.f;
  int j = lane>>3, hh = lane&7;

  // per-(lane) head base: base_h = pA[h] + pB[h]/3  (consecutive 4B loads across h)
  const float* pn = pt + (size_t)(type*NT+n)*16;
  float baseh = pn[hh] + pn[8+hh]*third;

  // ---- Pass A: per-lane online (m,den) over its own edges, then merge over j ----
  float m = -1e30f, den = 0.f;
  for(int s=off+j; s<end; s+=8){
    int2 mm = mids_g[s];
    float q1 = pt[(size_t)mm.x*16 + 8 + hh];
    float q2 = pt[(size_t)mm.y*16 + 8 + hh];
    float e = baseh + (q1+q2)*third;
    float ev = e>0.f? e : 0.2f*e;
    float mn = fmaxf(m, ev);
    den = den*__expf(m-mn) + __expf(ev-mn);
    m = mn;
  }
  #pragma unroll
  for(int o8=8;o8<=32;o8<<=1){
    float om = __shfl_xor(m, o8, 64);
    float od = __shfl_xor(den, o8, 64);
    float mn = fmaxf(m, om);
    den = den*__expf(m-mn) + od*__expf(om-mn);
    m = mn;
  }
  float invD = 1.f/fmaxf(den, 1e-9f);    // (M,D) now uniform per head across j

  // ---- Pass B: chunks of 8 edges ----
  float o[8]={0.f,0.f,0.f,0.f,0.f,0.f,0.f,0.f};
  for(int base=off; base<end; base+=8){
    // B1 (parallel): w for 8 edges x 8 heads, one expf
    int s = base+j;
    float w = 0.f;
    if(s<end){
      int2 mm = mids_g[s];
      float q1 = pt[(size_t)mm.x*16 + 8 + hh];
      float q2 = pt[(size_t)mm.y*16 + 8 + hh];
      float e = baseh + (q1+q2)*third;
      float ev = e>0.f? e : 0.2f*e;
      w = __expf(ev-m)*invD;
    }
    // B2 (serial over the chunk's edges): gathers + shuffle-broadcast alpha + fma
    int cnt = min(8, end-base);
    for(int k=0;k<cnt;k++){
      int2 mm = mids_g[base+k];
      float hvm = h[(size_t)mm.x*64+lane] + h[(size_t)mm.y*64+lane];
      #pragma unroll
      for(int q=0;q<8;q++){
        float alpha = __shfl(w, k*8+q, 64);
        o[q] += alpha*hvm;
      }
    }
  }

  float hn = h[((size_t)type*NT+(size_t)n)*64+lane];
  #pragma unroll
  for(int q=0;q<8;q++){
    float v = (end>off)? (o[q] + hn)*third : 0.f;
    v = v>0.f? v : (__expf(v)-1.f);
    stp[(size_t)n*512 + q*64 + lane] = v;
  }
}

// -------- pack mpW (512x128 f32) into MFMA B-fragment layout (bf16); zero accv -----
__global__ __launch_bounds__(256) void k_pack(const float* __restrict__ W, short* __restrict__ bpk,
                                              float* __restrict__ accv){
  int tid = blockIdx.x*256+threadIdx.x;   // 0..8191
  int lane = tid&63; int c=(tid>>6)&7; int t=tid>>9;
  int kbase = t*32 + ((lane>>4)<<3);
  int col = c*16 + (lane&15);
  short8 v;
  #pragma unroll
  for(int jj=0;jj<8;jj++) v[jj]=f2bf(W[(size_t)(kbase+jj)*128+col]);
  ((short8*)bpk)[tid]=v;
  if(tid<256) accv[tid]=0.f;
}

// -------- bf16 MFMA + LDS-staged B: accv[p][col] += sum_n tanh(st@W + b) -----------
__global__ __launch_bounds__(256) void k_tanhmm(const float* __restrict__ st, const short* __restrict__ bpk,
                        const float* __restrict__ bias, float* __restrict__ accv){
  __shared__ short8 Bsh[2048];          // 4 kt-chunks x 8 c x 64 lanes x 16B = 32 KB
  int wave=threadIdx.x>>6, lane=threadIdx.x&63;
  int p=blockIdx.y;
  const float* stp = st + (size_t)p*NT*512;
  int row0 = (blockIdx.x*4+wave)*16;
  int active = (row0<NT);
  int rA = row0 + (lane&15); if(rA>NT-1) rA=NT-1;
  const float* arow = stp + (size_t)rA*512 + ((lane>>4)<<3);
  f32x4 acc[8];
  #pragma unroll
  for(int c=0;c<8;c++) acc[c]=(f32x4){0.f,0.f,0.f,0.f};
  const short8* bp = (const short8*)bpk;
  for(int kc=0;kc<16;kc+=4){
    __syncthreads();
    #pragma unroll
    for(int q=0;q<8;q++){
      int idx = q*256 + threadIdx.x;
      Bsh[idx] = bp[(size_t)kc*512 + idx];
    }
    __syncthreads();
    if(active){
      #pragma unroll
      for(int ktl=0;ktl<4;ktl++){
        int kt=kc+ktl;
        float4 f0 = *(const float4*)(arow + kt*32);
        float4 f1 = *(const float4*)(arow + kt*32 + 4);
        short8 a;
        a[0]=f2bf(f0.x); a[1]=f2bf(f0.y); a[2]=f2bf(f0.z); a[3]=f2bf(f0.w);
        a[4]=f2bf(f1.x); a[5]=f2bf(f1.y); a[6]=f2bf(f1.z); a[7]=f2bf(f1.w);
        #pragma unroll
        for(int c=0;c<8;c++){
          short8 bfr = Bsh[ktl*512 + c*64 + lane];
          acc[c]=__builtin_amdgcn_mfma_f32_16x16x32_bf16(a,bfr,acc[c],0,0,0);
        }
      }
    }
  }
  if(active){
    int rbase = row0 + ((lane>>4)<<2);
    int colb = lane&15;
    #pragma unroll
    for(int c=0;c<8;c++){
      int col=c*16+colb;
      float bb=bias[col];
      float s=0.f;
      #pragma unroll
      for(int r=0;r<4;r++){
        if(rbase+r<NT) s += fast_tanh(acc[c][r]+bb);
      }
      s += __shfl_xor(s,16,64);
      s += __shfl_xor(s,32,64);
      if(lane<16) atomicAdd(&accv[p*128+col], s);
    }
  }
}

// -------- beta = softmax over P of (mean tanh)·q ------------------------------------
__global__ void k_beta(const float* __restrict__ accv, const float* __restrict__ q,
                       float* __restrict__ beta, int slot){
  __shared__ float r0[128], r1[128];
  int t=threadIdx.x;
  r0[t]=accv[t]*q[t]; r1[t]=accv[128+t]*q[t];
  __syncthreads();
  for(int off=64;off>0;off>>=1){
    if(t<off){ r0[t]+=r0[t+off]; r1[t]+=r1[t+off]; }
    __syncthreads();
  }
  if(t==0){
    float s0=r0[0]/(float)NT, s1=r1[0]/(float)NT;
    float mm=fmaxf(s0,s1);
    float e0=__expf(s0-mm), e1=__expf(s1-mm);
    float d=e0+e1;
    beta[slot*2]=e0/d; beta[slot*2+1]=e1/d;
  }
}

// -------- final: logits[t] = (b0*st0[row]+b1*st1[row]) @ lW1 + lb1 -----------------
__global__ __launch_bounds__(64) void k_final(const float* __restrict__ st0, const float* __restrict__ st1,
      const float* __restrict__ beta, const float* __restrict__ lW1, const float* __restrict__ lb1,
      const int* __restrict__ tgt, float* __restrict__ out){
  int t=blockIdx.x; int lane=threadIdx.x;
  int row=tgt[t];
  float b0=beta[6], b1=beta[7];
  float acc[8]={0.f,0.f,0.f,0.f,0.f,0.f,0.f,0.f};
  #pragma unroll
  for(int kk=0;kk<8;kk++){
    int k=kk*64+lane;
    float hm=b0*st0[(size_t)row*512+k]+b1*st1[(size_t)row*512+k];
    const float4* wp=(const float4*)(lW1+(size_t)k*8);
    float4 w0=wp[0], w1=wp[1];
    acc[0]+=hm*w0.x; acc[1]+=hm*w0.y; acc[2]+=hm*w0.z; acc[3]+=hm*w0.w;
    acc[4]+=hm*w1.x; acc[5]+=hm*w1.y; acc[6]+=hm*w1.z; acc[7]+=hm*w1.w;
  }
  #pragma unroll
  for(int c=0;c<8;c++){
    #pragma unroll
    for(int off=32;off>0;off>>=1) acc[c]+=__shfl_xor(acc[c],off,64);
  }
  if(lane<8){
    float v=0.f;
    #pragma unroll
    for(int c=0;c<8;c++) if(lane==c) v=acc[c];
    out[t*8+lane]=v+lb1[lane];
  }
}

extern "C" void kernel_launch(void* const* d_in, const int* in_sizes, int n_in,
                              void* d_out, int out_size, void* d_ws, size_t ws_size,
                              hipStream_t stream) {
  const float* X0=(const float*)d_in[0];
  const float* X1=(const float*)d_in[1];
  const float* X2=(const float*)d_in[2];
  const float* fcW0=(const float*)d_in[3]; const float* fcb0=(const float*)d_in[4];
  const float* fcW1=(const float*)d_in[5]; const float* fcb1=(const float*)d_in[6];
  const float* fcW2=(const float*)d_in[7]; const float* fcb2=(const float*)d_in[8];
  const float* attn1=(const float*)d_in[9];
  const float* attn2=(const float*)d_in[10];
  const float* mpW=(const float*)d_in[11];
  const float* mpb=(const float*)d_in[12];
  const float* mpq=(const float*)d_in[13];
  const float* lW0=(const float*)d_in[14]; const float* lb0=(const float*)d_in[15];
  const float* lW1=(const float*)d_in[16]; const float* lb1=(const float*)d_in[17];
  const int* mp=(const int*)d_in[18];
  const int* tgt=(const int*)d_in[19];
  float* out=(float*)d_out;

  // workspace layout (total ~273.3 MB). Liveness-checked carve-outs:
  char* ws=(char*)d_ws;
  float* h0   =(float*)(ws+0);              // N*64 f32      (live from k_mm64f on)
  float* h1   =(float*)(ws+26112000);       // N*64 f32
  float* ptab =(float*)(ws+52224000);       // 6*N*16 f32
  int*   offs =(int*  )(ws+91392000);       // 6*(NT+1)
  int*   counts=(int* )(ws+92208128);       // 6*NT (live during CSR build ONLY)
  int2*  mids =(int2* )(ws+100224128);      // 6*E int2
  float* st   =(float*)(ws+133824128);      // 2*NT*512 f32  (live from k_seg on)
  short* bpk  =(short*)(ws+273088128);      // mpW fragments
  float* accv =(float*)(ws+273219200);      // 2*128 f32
  float* beta =(float*)(ws+273220224);      // 8 f32
  // packed fc weights: counts region, first written AFTER k_scatter (counts dead). OK.
  short* wpk0 =(short*)(ws+92208128);       // [.., +128KB)  K=512
  short* wpk1 =(short*)(ws+92339200);       // [.., +64KB)   K=256
  short* wpkL =(short*)(ws+92404736);       // [.., +128KB)  K=512
  short* wpk2 =(short*)(ws+92535808);       // [.., +32KB)   K=128
  // bsum: used ONLY during CSR build; placed in st region (first written by k_seg later)
  int*   bsum =(int*  )(ws+133824128);      // 6*NBLK ints = 3192 B

  dim3 b256(256);
  // CSR build (mp_idx is layer-invariant; built once per launch)
  k_zero<<<dim3((6*NT+255)/256),b256,0,stream>>>(counts,6*NT);
  k_hist<<<dim3((NE+255)/256,6),b256,0,stream>>>(mp,counts);
  k_blkred<<<dim3(NBLK,6),b256,0,stream>>>(counts,bsum);
  k_scansums<<<dim3(6),b256,0,stream>>>(bsum);
  k_scanapply<<<dim3(NBLK,6),b256,0,stream>>>(counts,bsum,offs);
  k_scatter<<<dim3((NE+255)/256,6),b256,0,stream>>>(mp,offs,counts,mids);

  // pack fc weights (counts region dead from here on)
  k_packWall<<<dim3(16,4),b256,0,stream>>>(fcW0,fcW1,fcW2,lW0,wpk0,wpk1,wpk2,wpkL);

  // per-type feature transforms -> h0 (MFMA split-bf16)
  k_mm64f<<<dim3(532),b256,0,stream>>>(X0,wpk0,fcb0,h0,NT,512,0);
  k_mm64f<<<dim3(532),b256,0,stream>>>(X1,wpk1,fcb1,h0+(size_t)NT*64,NT,256,0);
  k_mm64f<<<dim3(532),b256,0,stream>>>(X2,wpk2,fcb2,h0+(size_t)2*NT*64,NT,128,0);

  // ---- layer 0 ----
  k_pre<<<dim3((NN+255)/256),b256,0,stream>>>(h0,attn1,attn2,ptab,6);
  for(int type=0;type<3;type++){
    k_seg<<<dim3(NT/4,2),b256,0,stream>>>(offs,ptab,mids,h0,st,type);
    k_pack<<<dim3(32),b256,0,stream>>>(mpW+(size_t)(0*3+type)*512*128,bpk,accv);
    k_tanhmm<<<dim3(532,2),b256,0,stream>>>(st,bpk,mpb+(0*3+type)*128,accv);
    k_beta<<<dim3(1),dim3(128),0,stream>>>(accv,mpq+(0*3+type)*128,beta,type);
    k_mm64fB<<<dim3(532),b256,0,stream>>>(st,st+(size_t)NT*512,beta,type,wpkL,lb0,
                                          h1+(size_t)type*NT*64,NT,1);
  }

  // ---- layer 1 (only type 0 reaches the output) ----
  k_pre<<<dim3((NN+255)/256),b256,0,stream>>>(h1,attn1+(size_t)6*512,attn2+(size_t)6*512,ptab,2);
  k_seg<<<dim3(NT/4,2),b256,0,stream>>>(offs,ptab,mids,h1,st,0);
  k_pack<<<dim3(32),b256,0,stream>>>(mpW+(size_t)(1*3+0)*512*128,bpk,accv);
  k_tanhmm<<<dim3(532,2),b256,0,stream>>>(st,bpk,mpb+(1*3+0)*128,accv);
  k_beta<<<dim3(1),dim3(128),0,stream>>>(accv,mpq+(1*3+0)*128,beta,3);
  k_final<<<dim3(NTGT),dim3(64),0,stream>>>(st,st+(size_t)NT*512,beta,lW1,lb1,tgt,out);
}